// Round 1
// baseline (200.279 us; speedup 1.0000x reference)
//
#include <hip/hip_runtime.h>

// TorchGrouper: G=40000 grid points, O=64 offsets (4^3 hollow cube), C=64 channels.
// voxel_maps: int32 [2,40,400,400]; grid_positions: f32 [G,4] (b,z,y,x);
// features: f32 [100000,64].
// Outputs concat: sampled_features [1,64,G,64] | gpf [1,3,G,64] | empty_mask [G]
// Thread = (g,o); wave (64 lanes) = one g, lane = o. Stores along tid are coalesced.

constexpr int G  = 40000;
constexpr int O  = 64;
constexpr int C  = 64;
constexpr int VZ = 40, VY = 400, VX = 400;
constexpr long long GO = (long long)G * O;

__global__ __launch_bounds__(256) void grouper_kernel(
    const int*   __restrict__ vox,
    const float* __restrict__ gpos,
    const float* __restrict__ feat,
    float*       __restrict__ out)
{
    const int tid = blockIdx.x * 256 + threadIdx.x;   // tid = g*64 + o
    const int g = tid >> 6;
    const int o = tid & 63;

    // offset decode: r = {-3,-2,1,2}; o = iz*16 + iy*4 + ix
    // offsets row = (0, rx, ry, rz) added to (b, z, y, x)
    const int rtab4[4] = {-3, -2, 1, 2};
    const int rx = rtab4[o & 3];
    const int ry = rtab4[(o >> 2) & 3];
    const int rz = rtab4[(o >> 4) & 3];

    const float4 p = ((const float4*)gpos)[g];        // (b, z, y, x), 16B aligned
    const float zf = p.y + (float)rx;
    const float yf = p.z + (float)ry;
    const float xf = p.w + (float)rz;

    // trunc-toward-zero casts match jnp .astype(int32) / torch .long()
    const int bi = (int)p.x;
    const int zi = min(max((int)zf, 0), VZ - 1);
    const int yi = min(max((int)yf, 0), VY - 1);
    const int xi = min(max((int)xf, 0), VX - 1);

    const int idx = vox[((bi * VZ + zi) * VY + yi) * VX + xi];

    // ---- gpf output: [1,3,G,O], channels (z,y,x) frac + quirk (+0, +rx, +ry)
    float* gout = out + (size_t)C * GO;
    __builtin_nontemporal_store(zf - truncf(zf),               gout + tid);
    __builtin_nontemporal_store(yf - truncf(yf) + (float)rx,   gout + GO + tid);
    __builtin_nontemporal_store(xf - truncf(xf) + (float)ry,   gout + 2 * GO + tid);

    // ---- empty mask: sum_o (idx+1) == 0  <=>  all lanes idx == -1
    const int allm1 = __all(idx == -1);
    if (o == 0) gout[3 * GO + g] = allm1 ? 1.0f : 0.0f;

    // ---- sampled_features: out[c*GO + tid] = idx<0 ? 0 : feat[idx*C + c]
    const bool empty = (idx < 0);
    const int row = empty ? 0 : idx;
    const float4* frow = (const float4*)(feat + (size_t)row * C);  // 256B-aligned row
    float* op = out + tid;
    #pragma unroll
    for (int c4 = 0; c4 < C / 4; ++c4) {
        float4 v = frow[c4];
        v.x = empty ? 0.0f : v.x;
        v.y = empty ? 0.0f : v.y;
        v.z = empty ? 0.0f : v.z;
        v.w = empty ? 0.0f : v.w;
        __builtin_nontemporal_store(v.x, op + (size_t)(4 * c4 + 0) * GO);
        __builtin_nontemporal_store(v.y, op + (size_t)(4 * c4 + 1) * GO);
        __builtin_nontemporal_store(v.z, op + (size_t)(4 * c4 + 2) * GO);
        __builtin_nontemporal_store(v.w, op + (size_t)(4 * c4 + 3) * GO);
    }
}

extern "C" void kernel_launch(void* const* d_in, const int* in_sizes, int n_in,
                              void* d_out, int out_size, void* d_ws, size_t ws_size,
                              hipStream_t stream) {
    const int*   vox  = (const int*)d_in[0];
    const float* gpos = (const float*)d_in[1];
    const float* feat = (const float*)d_in[2];
    float*       out  = (float*)d_out;

    const int total = (int)GO;                 // 2,560,000 threads, one per (g,o)
    const int block = 256;
    const int grid  = (total + block - 1) / block;   // 10,000 blocks
    grouper_kernel<<<grid, block, 0, stream>>>(vox, gpos, feat, out);
}

// Round 3
// 200.027 us; speedup vs baseline: 1.0013x; 1.0013x over previous
//
#include <hip/hip_runtime.h>

// TorchGrouper: G=40000, O=64 offsets (4^3 hollow cube), C=64 channels.
// vox: int32 [2,40,400,400]; gpos: f32 [G,4] (b,z,y,x); feat: f32 [100000,64].
// Out concat: sampled_features [1,64,G,64] | gpf [1,3,G,64] | empty_mask [G]
// Wave = one g, lane = o. Feature path goes through a swizzled LDS transpose:
//   Phase A: coalesced row loads (8 rows/instr, each 64B line touched once)
//   Phase B: float4 stores along o (dwordx4, 1KB/wave-instr)

typedef float f32x4 __attribute__((ext_vector_type(4)));

constexpr int G  = 40000;
constexpr int C  = 64;
constexpr int VZ = 40, VY = 400, VX = 400;
constexpr size_t GO = (size_t)G * 64;

__global__ __launch_bounds__(256) void grouper_kernel(
    const int*   __restrict__ vox,
    const float* __restrict__ gpos,
    const float* __restrict__ feat,
    float*       __restrict__ out)
{
    __shared__ __align__(16) float lds[4][64 * 32];   // 32 KB/block: per-wave 64rows x 32cols

    const int wid  = threadIdx.x >> 6;
    const int lane = threadIdx.x & 63;
    const int g = blockIdx.x * 4 + wid;
    const int o = lane;

    // offsets r = {-3,-2,1,2}
    const int rtab4[4] = {-3, -2, 1, 2};
    const int rx = rtab4[o & 3];          // added to z
    const int ry = rtab4[(o >> 2) & 3];   // added to y
    const int rz = rtab4[(o >> 4) & 3];   // added to x

    const float4 p = ((const float4*)gpos)[g];        // (b,z,y,x)
    const float zf = p.y + (float)rx;
    const float yf = p.z + (float)ry;
    const float xf = p.w + (float)rz;

    const int bi = (int)p.x;                          // trunc-toward-zero
    const int zi = min(max((int)zf, 0), VZ - 1);
    const int yi = min(max((int)yf, 0), VY - 1);
    const int xi = min(max((int)xf, 0), VX - 1);

    const int idx = vox[((bi * VZ + zi) * VY + yi) * VX + xi];

    // ---- gpf [1,3,G,64]: (z,y,x) frac + quirk (+0, +rx, +ry); empty mask
    float* gout = out + C * GO;
    const size_t t = (size_t)g * 64 + o;
    __builtin_nontemporal_store(zf - truncf(zf),             gout + t);
    __builtin_nontemporal_store(yf - truncf(yf) + (float)rx, gout + GO + t);
    __builtin_nontemporal_store(xf - truncf(xf) + (float)ry, gout + 2 * GO + t);
    const int allm1 = __all(idx == -1);
    if (o == 0) gout[3 * GO + g] = allm1 ? 1.0f : 0.0f;

    // ---- sampled_features via LDS transpose
    float* tile = lds[wid];
    const int d  = lane >> 3;   // phase A: row-within-group (0..7)
    const int c4 = lane & 7;    // phase A: col group (0..7)
    const int q  = lane >> 4;   // phase B: col low bits (0..3)
    const int m  = lane & 15;   // phase B: o-group (0..15)

    #pragma unroll
    for (int chunk = 0; chunk < 2; ++chunk) {
        // Phase A: 8 rows per instruction, 16B/lane, swizzled LDS write.
        #pragma unroll
        for (int i = 0; i < 8; ++i) {
            const int r    = i * 8 + d;               // LDS row = offset index o
            const int ridx = __shfl(idx, r);
            const bool emp = ridx < 0;
            const int  rr  = emp ? 0 : ridx;
            f32x4 v = *(const f32x4*)(feat + (size_t)rr * C + chunk * 32 + c4 * 4);
            if (emp) { v.x = 0.0f; v.y = 0.0f; v.z = 0.0f; v.w = 0.0f; }
            const int cs = c4 ^ ((r >> 2) & 7);       // bank swizzle
            *(f32x4*)(tile + r * 32 + cs * 4) = v;
        }
        asm volatile("s_waitcnt lgkmcnt(0)" ::: "memory");

        // Phase B: gather 4 o's per lane from LDS, 1KB dwordx4 nt store.
        #pragma unroll
        for (int i = 0; i < 8; ++i) {
            const int ip = (i ^ (m & 7)) * 4 + q;     // swizzled col for rows 4m..4m+3
            f32x4 sv;
            sv.x = tile[(m * 4 + 0) * 32 + ip];
            sv.y = tile[(m * 4 + 1) * 32 + ip];
            sv.z = tile[(m * 4 + 2) * 32 + ip];
            sv.w = tile[(m * 4 + 3) * 32 + ip];
            const size_t c = (size_t)(chunk * 32 + i * 4 + q);
            __builtin_nontemporal_store(sv, (f32x4*)(out + c * GO + (size_t)g * 64 + m * 4));
        }
        asm volatile("s_waitcnt lgkmcnt(0)" ::: "memory");
    }
}

extern "C" void kernel_launch(void* const* d_in, const int* in_sizes, int n_in,
                              void* d_out, int out_size, void* d_ws, size_t ws_size,
                              hipStream_t stream) {
    const int*   vox  = (const int*)d_in[0];
    const float* gpos = (const float*)d_in[1];
    const float* feat = (const float*)d_in[2];
    float*       out  = (float*)d_out;

    const int grid = G / 4;   // 10000 blocks x 256 threads; wave = one g
    grouper_kernel<<<grid, 256, 0, stream>>>(vox, gpos, feat, out);
}